// Round 1
// baseline (461.302 us; speedup 1.0000x reference)
//
#include <hip/hip_runtime.h>
#include <cmath>

// SSIM over (32,3,512,512) f32 pairs, 11x11 separable gaussian, valid conv,
// scalar mean output. Fully fused: one pass over inputs, tile-local separable
// conv in LDS, double-precision global accumulation.

#define HH 512
#define WW 512
#define OH 502           // 512 - 11 + 1
#define OW 502
#define NC 96            // 32 * 3
#define TX 32            // output tile cols
#define TY 32            // output tile rows
#define IN 42            // TY + 10 halo
#define SPAD 44          // row stride (floats) for input tiles
#define HPAD 33          // row stride (floats) for horizontal-pass arrays

struct GaussW { float g[11]; };

__global__ __launch_bounds__(256) void ssim_kernel(
        const float* __restrict__ X, const float* __restrict__ Y,
        double* __restrict__ acc, GaussW gw) {
    __shared__ float sX[IN][SPAD];
    __shared__ float sY[IN][SPAD];
    __shared__ float h0[IN][HPAD];   // conv_h(x)
    __shared__ float h1[IN][HPAD];   // conv_h(y)
    __shared__ float h2[IN][HPAD];   // conv_h(x*x)
    __shared__ float h3[IN][HPAD];   // conv_h(y*y)
    __shared__ float h4[IN][HPAD];   // conv_h(x*y)
    __shared__ double wsum[4];

    const int tid = threadIdx.x;
    const int R0 = blockIdx.y * TY;
    const int C0 = blockIdx.x * TX;
    const float* Xp = X + (size_t)blockIdx.z * (HH * WW);
    const float* Yp = Y + (size_t)blockIdx.z * (HH * WW);

    // ---- Phase 1: load 42x42 halo tile, normalize [-1,1] -> [0,1] ----
    for (int idx = tid; idx < IN * IN; idx += 256) {
        int r = idx / IN, c = idx % IN;
        int gr = R0 + r; if (gr > HH - 1) gr = HH - 1;   // clamp; clamped rows feed
        int gc = C0 + c; if (gc > WW - 1) gc = WW - 1;   // only discarded outputs
        float xv = (Xp[gr * WW + gc] + 1.0f) * 0.5f;
        float yv = (Yp[gr * WW + gc] + 1.0f) * 0.5f;
        sX[r][c] = xv;
        sY[r][c] = yv;
    }
    __syncthreads();

    // ---- Phase 2: horizontal 11-tap conv on 5 maps, 42 rows x 32 cols ----
    for (int idx = tid; idx < IN * TX; idx += 256) {
        int r = idx >> 5, c = idx & 31;   // lanes consecutive in c: conflict-free
        float ax = 0.f, ay = 0.f, axx = 0.f, ayy = 0.f, axy = 0.f;
        #pragma unroll
        for (int k = 0; k < 11; ++k) {
            float g = gw.g[k];
            float x = sX[r][c + k];
            float y = sY[r][c + k];
            float gx = g * x, gy = g * y;
            ax += gx;
            ay += gy;
            axx = fmaf(gx, x, axx);
            ayy = fmaf(gy, y, ayy);
            axy = fmaf(gx, y, axy);
        }
        h0[r][c] = ax; h1[r][c] = ay; h2[r][c] = axx; h3[r][c] = ayy; h4[r][c] = axy;
    }
    __syncthreads();

    // ---- Phase 3: vertical 11-tap conv; each thread owns 4 rows of one col ----
    const int c  = tid & 31;
    const int r0 = (tid >> 5) * 4;        // 0,4,...,28
    float m1[4]  = {0.f, 0.f, 0.f, 0.f};
    float m2[4]  = {0.f, 0.f, 0.f, 0.f};
    float e11[4] = {0.f, 0.f, 0.f, 0.f};
    float e22[4] = {0.f, 0.f, 0.f, 0.f};
    float e12[4] = {0.f, 0.f, 0.f, 0.f};
    #pragma unroll
    for (int k = 0; k < 14; ++k) {        // rows r0 .. r0+13 feed outputs r0..r0+3
        float v0 = h0[r0 + k][c];
        float v1 = h1[r0 + k][c];
        float v2 = h2[r0 + k][c];
        float v3 = h3[r0 + k][c];
        float v4 = h4[r0 + k][c];
        #pragma unroll
        for (int j = 0; j < 4; ++j) {
            int kk = k - j;
            if (kk >= 0 && kk < 11) {     // statically resolved after unroll
                float g = gw.g[kk];
                m1[j]  = fmaf(g, v0, m1[j]);
                m2[j]  = fmaf(g, v1, m2[j]);
                e11[j] = fmaf(g, v2, e11[j]);
                e22[j] = fmaf(g, v3, e22[j]);
                e12[j] = fmaf(g, v4, e12[j]);
            }
        }
    }

    const float C1 = 1.0e-4f;  // (0.01*1.0)^2
    const float C2 = 9.0e-4f;  // (0.03*1.0)^2
    double tsum = 0.0;
    #pragma unroll
    for (int j = 0; j < 4; ++j) {
        float mu1 = m1[j], mu2 = m2[j];
        float mu1s = mu1 * mu1, mu2s = mu2 * mu2, mu12 = mu1 * mu2;
        float s1  = e11[j] - mu1s;
        float s2  = e22[j] - mu2s;
        float s12 = e12[j] - mu12;
        float cs  = (2.0f * s12 + C2) / (s1 + s2 + C2);
        float sm  = ((2.0f * mu12 + C1) / (mu1s + mu2s + C1)) * cs;
        int gr = R0 + r0 + j, gc = C0 + c;
        if (gr < OH && gc < OW) tsum += (double)sm;
    }

    // ---- block reduction (double) + one f64 atomic per block ----
    #pragma unroll
    for (int off = 32; off > 0; off >>= 1)
        tsum += __shfl_down(tsum, off, 64);
    if ((tid & 63) == 0) wsum[tid >> 6] = tsum;
    __syncthreads();
    if (tid == 0) {
        double t = wsum[0] + wsum[1] + wsum[2] + wsum[3];
        atomicAdd(acc, t);
    }
}

__global__ void ssim_finalize(const double* __restrict__ acc,
                              float* __restrict__ out) {
    out[0] = (float)(acc[0] * (1.0 / (double)((long long)NC * OH * OW)));
}

extern "C" void kernel_launch(void* const* d_in, const int* in_sizes, int n_in,
                              void* d_out, int out_size, void* d_ws, size_t ws_size,
                              hipStream_t stream) {
    const float* X = (const float*)d_in[0];
    const float* Y = (const float*)d_in[1];
    float* out = (float*)d_out;
    double* acc = (double*)d_ws;

    // d_ws is re-poisoned to 0xAA before every timed launch: zero our accumulator.
    hipMemsetAsync(acc, 0, sizeof(double), stream);

    // Gaussian weights (win=11, sigma=1.5), computed in f64, passed by value.
    GaussW gw;
    {
        double g[11], s = 0.0;
        for (int i = 0; i < 11; ++i) {
            double d = (double)(i - 5);
            g[i] = exp(-d * d / (2.0 * 1.5 * 1.5));
            s += g[i];
        }
        for (int i = 0; i < 11; ++i) gw.g[i] = (float)(g[i] / s);
    }

    dim3 grid((OW + TX - 1) / TX, (OH + TY - 1) / TY, NC);
    ssim_kernel<<<grid, dim3(256), 0, stream>>>(X, Y, acc, gw);
    ssim_finalize<<<1, 1, 0, stream>>>(acc, out);
}